// Round 10
// baseline (337.379 us; speedup 1.0000x reference)
//
#include <hip/hip_runtime.h>
#include <hip/hip_bf16.h>

// Problem constants
constexpr int BB = 8192;   // batch rows
constexpr int CC = 2048;   // classes
constexpr int FF = 2048;   // features (K)

typedef __bf16 bf16x8 __attribute__((ext_vector_type(8)));
typedef float  f32x4  __attribute__((ext_vector_type(4)));

typedef __attribute__((address_space(1))) unsigned int gu32;
typedef __attribute__((address_space(3))) unsigned int lu32;

// async global->LDS, 16B per lane. LDS side is wave-uniform base + lane*16.
__device__ __forceinline__ void async_copy16(const void* g, void* l) {
    __builtin_amdgcn_global_load_lds(
        (gu32*)(unsigned long long)g,
        (lu32*)(unsigned int)(unsigned long long)l,
        16, 0, 0);
}

// ---------------------------------------------------------------------------
// prep (merged): rows [0,BB) = x scaled by 1/var; rows [BB,BB+CC) = means.
// emit bf16 row + fp32 sum of squares. 256 thr/row, 8 elems/thread.
// ---------------------------------------------------------------------------
__global__ void prep_rows(const float* __restrict__ x,
                          const float* __restrict__ means,
                          unsigned short* __restrict__ xb,
                          unsigned short* __restrict__ mb,
                          float* __restrict__ x2,
                          float* __restrict__ m2,
                          const float* __restrict__ varp) {
    const int blk = blockIdx.x;
    const bool isx = blk < BB;
    const int row = isx ? blk : blk - BB;
    const int t = threadIdx.x;
    const float scale = isx ? (1.0f / varp[0]) : 1.0f;
    const float* in = isx ? x : means;
    unsigned short* outb = isx ? xb : mb;
    const size_t base = (size_t)row * FF + (size_t)t * 8;
    const float4 a = *(const float4*)(in + base);
    const float4 b = *(const float4*)(in + base + 4);
    float v[8] = {a.x * scale, a.y * scale, a.z * scale, a.w * scale,
                  b.x * scale, b.y * scale, b.z * scale, b.w * scale};
    float s = 0.0f;
    bf16x8 h;
#pragma unroll
    for (int i = 0; i < 8; ++i) {
        s += v[i] * v[i];
        h[i] = (__bf16)v[i];
    }
    *(bf16x8*)(outb + base) = h;
#pragma unroll
    for (int off = 32; off > 0; off >>= 1) s += __shfl_down(s, off);
    __shared__ float red[4];
    if ((t & 63) == 0) red[t >> 6] = s;
    __syncthreads();
    if (t == 0) {
        float tot = (red[0] + red[1]) + (red[2] + red[3]);
        if (isx) x2[row] = tot; else m2[row] = tot;
    }
}

// ---------------------------------------------------------------------------
// GEMM cross[b][c] = sum_f xs[b][f]*means[c][f]  (row-major, K contig: NT)
//
// 256x128 tile (M x N), 512 thr = 8 waves (4M x 2N), per-wave output 64x64
// via 4x4 of v_mfma_f32_16x16x32_bf16.  K in chunks of 32 through a RING of
// 3 LDS slots (slot = A 256x32 + B 128x32 bf16 = 24 KB; 72 KB total) ->
// TWO blocks/CU (grid 512 = 2/CU exact, __launch_bounds__(512,4)).
//
// WHY 2 blocks/CU (R6 lesson): two schedule variants (coarse + m201-fine)
// both landed ~600 TF at 1 block/CU — the exposed cost is barrier convoy +
// staging latency + 525KB serial epilogue, none of which another *phase*
// can hide, but a co-resident BLOCK can (m114: independent waves co-schedule
// MFMA/VALU/VMEM).  Epilogue & prologue also overlap the other block's loop.
//
// Pipeline: counted vmcnt ring (T4), coarse 1-barrier/chunk (fine split was
// neutral).  Per chunk u: vmcnt(3) [chunk u's 3 loads landed; u+1 in
// flight] | s_barrier | schedbar | 8 ds_read_b128 | STAGE(u+2 -> slot
// (u+2)%3: its readers finished reads before passing THIS barrier) |
// lgkmcnt(0) schedbar | setprio{16 MFMA}.  Tail: vmcnt(3), vmcnt(0).
//
// LDS rows 64 B (4 x 16B chunks); phys chunk c' = c ^ ((row>>1)&3): frag
// reads 2-way banked = free (m136); XOR pre-applied to global source (DMA
// dest linear, rule #21).
//
// Block->XCD map: xcd = bx&7, lid = bx>>3 (0..63); bm = xcd*4 + lid>>4,
// bn = lid&15.  Per XCD: 4 A-panels (4 MB) + 16 B-panels (8 MB); per-chunk
// cadence working set 4x16KB + 16x8KB = 192 KB -> L2-resident slices.
// ---------------------------------------------------------------------------
__global__ __launch_bounds__(512, 4) void gemm_epi(
    const unsigned short* __restrict__ A,   // xs  bf16 [BB][FF]
    const unsigned short* __restrict__ Bm,  // means bf16 [CC][FF]
    const float* __restrict__ x2,           // [BB]
    const float* __restrict__ m2,           // [CC]
    float* __restrict__ expo,               // [BB][CC]
    float* __restrict__ cum) {              // [BB][CC]
    __shared__ __align__(16) unsigned short As[3][256 * 32];
    __shared__ __align__(16) unsigned short Bs[3][128 * 32];

    const int t = threadIdx.x;
    const int wave = t >> 6, lane = t & 63;
    const int bx = blockIdx.x;
    const int xcd = bx & 7, lid = bx >> 3;              // lid 0..63
    const int bm = xcd * 4 + (lid >> 4);                // 0..31
    const int bn = lid & 15;                            // 0..15
    const int rowA0 = bm * 256, colB0 = bn * 128;
    const int wm = wave >> 1, wn = wave & 1;            // 4M x 2N

    // staging: wave writes 16 rows x 64B linear per instruction.
    // lane -> row-in-group lane>>2, 16B-slot lane&3; source chunk is the
    // inverse swizzle  c = slot ^ ((sr>>1)&3)  (row bases are x16).
    const int sr = lane >> 2;                           // 0..15
    const int sc = ((lane & 3) ^ ((sr >> 1) & 3)) * 8;  // source col (shorts)
    const unsigned short* gA0 = A  + (size_t)(rowA0 +       wave * 16 + sr) * FF + sc;
    const unsigned short* gA1 = A  + (size_t)(rowA0 + 128 + wave * 16 + sr) * FF + sc;
    const unsigned short* gB0 = Bm + (size_t)(colB0 +       wave * 16 + sr) * FF + sc;
    const int ldsOff = wave * 16 * 32;                  // shorts

    // fragment reads (mfma 16x16x32: row = lane&15, k-half = lane>>4)
    const int rl = lane & 15, kb = lane >> 4;
    const int pcol = (kb ^ ((rl >> 1) & 3)) * 8;        // phys col (shorts)
    const int arow = (wm * 64 + rl) * 32 + pcol;
    const int brow = (wn * 64 + rl) * 32 + pcol;

    f32x4 acc[4][4] = {};

    auto STAGE = [&](int slot, int kc) {
        const int ko = kc * 32;
        async_copy16(gA0 + ko, &As[slot][ldsOff]);
        async_copy16(gA1 + ko, &As[slot][128 * 32 + ldsOff]);
        async_copy16(gB0 + ko, &Bs[slot][ldsOff]);
    };

    // one chunk: coarse phase (fine 2-phase split measured neutral, R6)
    auto CHUNK = [&](int slot, int nslot, int kc, int vm, bool do_stage) {
        if (vm == 3) asm volatile("s_waitcnt vmcnt(3)" ::: "memory");
        else         asm volatile("s_waitcnt vmcnt(0)" ::: "memory");
        __builtin_amdgcn_s_barrier();
        __builtin_amdgcn_sched_barrier(0);
        bf16x8 af[4], bfr[4];
#pragma unroll
        for (int i = 0; i < 4; ++i) af[i] = *(const bf16x8*)&As[slot][arow + i * 16 * 32];
#pragma unroll
        for (int j = 0; j < 4; ++j) bfr[j] = *(const bf16x8*)&Bs[slot][brow + j * 16 * 32];
        if (do_stage) STAGE(nslot, kc);
        asm volatile("s_waitcnt lgkmcnt(0)" ::: "memory");
        __builtin_amdgcn_sched_barrier(0);
        __builtin_amdgcn_s_setprio(1);
#pragma unroll
        for (int i = 0; i < 4; ++i)
#pragma unroll
            for (int j = 0; j < 4; ++j)
                acc[i][j] = __builtin_amdgcn_mfma_f32_16x16x32_bf16(af[i], bfr[j], acc[i][j], 0, 0, 0);
        __builtin_amdgcn_s_setprio(0);
    };

    // prologue: 2 chunks in flight (6 loads)
    STAGE(0, 0); STAGE(1, 1);

    // chunks 0..59 (stage 2..61), then peeled 60..63 (stage 62,63, none, none)
#pragma unroll 3
    for (int u = 0; u < 60; ++u)
        CHUNK(u % 3, (u + 2) % 3, u + 2, 3, true);
    CHUNK(0, 2, 62, 3, true);    // u=60
    CHUNK(1, 0, 63, 3, true);    // u=61
    CHUNK(2, 0, 0, 3, false);    // u=62 (62,63 in flight -> vmcnt(3))
    CHUNK(0, 0, 0, 0, false);    // u=63 (drain)

    // epilogue: C/D layout col = lane&15, row = (lane>>4)*4 + reg  [m89/m91]
    const int ln = lane & 15, lq = lane >> 4;
    const int grow0 = rowA0 + wm * 64 + lq * 4;
    const int gcol0 = colB0 + wn * 64 + ln;
    float m2v[4];
#pragma unroll
    for (int j = 0; j < 4; ++j) m2v[j] = m2[gcol0 + j * 16];

#pragma unroll
    for (int i = 0; i < 4; ++i) {
        float x2r[4];
#pragma unroll
        for (int r = 0; r < 4; ++r) x2r[r] = x2[grow0 + i * 16 + r];
#pragma unroll
        for (int j = 0; j < 4; ++j)
#pragma unroll
            for (int r = 0; r < 4; ++r) {
                const float d2 = x2r[r] + m2v[j] - 2.0f * acc[i][j][r];
                const float d = sqrtf(fmaxf(d2, 0.0f));
                const size_t idx = (size_t)(grow0 + i * 16 + r) * CC + (gcol0 + j * 16);
                __builtin_nontemporal_store(d, &cum[idx]);  // never re-read
                expo[idx] = -d;                              // re-read by softmax
            }
    }
}

// ---------------------------------------------------------------------------
// softmax over each row of exponent -> probs. one block (256 thr) per row.
// No max-subtraction: d = sqrt(x2+m2-2c) <= sqrt(~4500) < 68, so
// exp(-d) >= 3e-30 >> FLT_MIN — unshifted exp is safe and exact enough.
// ---------------------------------------------------------------------------
__global__ void softmax_rows(const float* __restrict__ e, float* __restrict__ p) {
    const int row = blockIdx.x;
    const int t = threadIdx.x;
    const size_t base = (size_t)row * CC + (size_t)t * 8;
    const float4 a = *(const float4*)(e + base);
    const float4 b = *(const float4*)(e + base + 4);
    float ev[8] = {__expf(a.x), __expf(a.y), __expf(a.z), __expf(a.w),
                   __expf(b.x), __expf(b.y), __expf(b.z), __expf(b.w)};
    float s = 0.0f;
#pragma unroll
    for (int i = 0; i < 8; ++i) s += ev[i];
#pragma unroll
    for (int off = 32; off > 0; off >>= 1) s += __shfl_down(s, off);
    __shared__ float reds[4];
    if ((t & 63) == 0) reds[t >> 6] = s;
    __syncthreads();
    s = (reds[0] + reds[1]) + (reds[2] + reds[3]);
    const float inv = 1.0f / s;

    f32x4 o0 = {ev[0] * inv, ev[1] * inv, ev[2] * inv, ev[3] * inv};
    f32x4 o1 = {ev[4] * inv, ev[5] * inv, ev[6] * inv, ev[7] * inv};
    __builtin_nontemporal_store(o0, (f32x4*)(p + base));
    __builtin_nontemporal_store(o1, (f32x4*)(p + base + 4));
}

// ---------------------------------------------------------------------------
extern "C" void kernel_launch(void* const* d_in, const int* in_sizes, int n_in,
                              void* d_out, int out_size, void* d_ws, size_t ws_size,
                              hipStream_t stream) {
    const float* x     = (const float*)d_in[0];   // [BB][FF]
    const float* means = (const float*)d_in[1];   // [CC][FF]
    const float* var   = (const float*)d_in[2];   // [1]
    float* out = (float*)d_out;

    // workspace layout: xb bf16 [BB*FF] | mb bf16 [CC*FF] | x2 f32[BB] | m2 f32[CC]
    unsigned short* xb = (unsigned short*)d_ws;
    unsigned short* mb = xb + (size_t)BB * FF;
    float* x2 = (float*)(mb + (size_t)CC * FF);
    float* m2 = x2 + BB;

    float* probs = out;                          // output 0
    float* expo  = out + (size_t)BB * CC;        // output 1
    float* cum   = expo + (size_t)BB * CC;       // output 2

    prep_rows<<<BB + CC, 256, 0, stream>>>(x, means, xb, mb, x2, m2, var);
    gemm_epi<<<(BB / 256) * (CC / 128), 512, 0, stream>>>(xb, mb, x2, m2, expo, cum);
    softmax_rows<<<BB, 256, 0, stream>>>(expo, probs);
}

// Round 13
// 331.956 us; speedup vs baseline: 1.0163x; 1.0163x over previous
//
#include <hip/hip_runtime.h>
#include <hip/hip_bf16.h>

// Problem constants
constexpr int BB = 8192;   // batch rows
constexpr int CC = 2048;   // classes
constexpr int FF = 2048;   // features (K)

typedef __bf16 bf16x8 __attribute__((ext_vector_type(8)));
typedef float  f32x4  __attribute__((ext_vector_type(4)));

typedef __attribute__((address_space(1))) unsigned int gu32;
typedef __attribute__((address_space(3))) unsigned int lu32;

// async global->LDS, 16B per lane. LDS side is wave-uniform base + lane*16.
__device__ __forceinline__ void async_copy16(const void* g, void* l) {
    __builtin_amdgcn_global_load_lds(
        (gu32*)(unsigned long long)g,
        (lu32*)(unsigned int)(unsigned long long)l,
        16, 0, 0);
}

// ---------------------------------------------------------------------------
// prep (merged): rows [0,BB) = x scaled by 1/var; rows [BB,BB+CC) = means.
// emit bf16 row + fp32 sum of squares. 256 thr/row, 8 elems/thread.
// ---------------------------------------------------------------------------
__global__ void prep_rows(const float* __restrict__ x,
                          const float* __restrict__ means,
                          unsigned short* __restrict__ xb,
                          unsigned short* __restrict__ mb,
                          float* __restrict__ x2,
                          float* __restrict__ m2,
                          const float* __restrict__ varp) {
    const int blk = blockIdx.x;
    const bool isx = blk < BB;
    const int row = isx ? blk : blk - BB;
    const int t = threadIdx.x;
    const float scale = isx ? (1.0f / varp[0]) : 1.0f;
    const float* in = isx ? x : means;
    unsigned short* outb = isx ? xb : mb;
    const size_t base = (size_t)row * FF + (size_t)t * 8;
    const float4 a = *(const float4*)(in + base);
    const float4 b = *(const float4*)(in + base + 4);
    float v[8] = {a.x * scale, a.y * scale, a.z * scale, a.w * scale,
                  b.x * scale, b.y * scale, b.z * scale, b.w * scale};
    float s = 0.0f;
    bf16x8 h;
#pragma unroll
    for (int i = 0; i < 8; ++i) {
        s += v[i] * v[i];
        h[i] = (__bf16)v[i];
    }
    *(bf16x8*)(outb + base) = h;
#pragma unroll
    for (int off = 32; off > 0; off >>= 1) s += __shfl_down(s, off);
    __shared__ float red[4];
    if ((t & 63) == 0) red[t >> 6] = s;
    __syncthreads();
    if (t == 0) {
        float tot = (red[0] + red[1]) + (red[2] + red[3]);
        if (isx) x2[row] = tot; else m2[row] = tot;
    }
}

// ---------------------------------------------------------------------------
// GEMM cross[b][c] = sum_f xs[b][f]*means[c][f]  (row-major, K contig: NT)
//
// R10 post-mortem: schedule (R2/R6) and occupancy (R10: 2 blk/CU, VGPR=64,
// gate passed) both NEUTRAL (~336 total); cold PMC shows MfmaUtil 5%,
// VALUBusy 4%.  Untried lever: REGISTER BLOCKING.  4x4 frags/wave costs
// 0.5 ds_read_b128 per MFMA -> per CU-chunk: reads 1536 cyc > MFMA 1242 cyc
// (LDS pipe oversubscribed 1.24x by construction).  This version: 8x4
// blocking (m201's choice) = 0.375 reads/MFMA -> 1152 vs 1242, MFMA-
// dominant.  Also 4 waves/block (not 8): barrier convoys half as long.
//
// 256x128 tile (M x N), 256 thr = 4 waves (2M x 2N), per-wave output 128x64
// via 8x4 of v_mfma_f32_16x16x32_bf16.  K in chunks of 32 through a RING of
// 3 LDS slots (slot = A 256x32 + B 128x32 bf16 = 24 KB; 72 KB total) ->
// 2 blocks/CU (grid 512 exact), __launch_bounds__(256,2) (~210 VGPR needed).
//
// Pipeline: counted vmcnt ring (T4), 1 barrier/chunk.  Per chunk u:
// vmcnt(6) [chunk u's 6 loads landed; u+1's 6 in flight] | s_barrier |
// schedbar | 12 ds_read_b128 | STAGE(u+2 -> slot (u+2)%3: its readers
// finished ds_reads before passing THIS barrier) | lgkmcnt(0) schedbar |
// setprio{32 MFMA}.  Tail: vmcnt(6), vmcnt(6), vmcnt(0).
//
// Staging: 6 rounds x (4 waves x 16 rows x 64B linear): rounds 0-3 = A rows
// 0-255, rounds 4-5 = B rows 0-127.  LDS rows 64 B (4 x 16B chunks); phys
// chunk c' = c ^ ((row>>1)&3): frag reads 2-way banked = free (m136); XOR
// pre-applied to global source (DMA dest linear, rule #21).
//
// Block->XCD map: xcd = bx&7, lid = bx>>3 (0..63); bm = xcd*4 + lid>>4,
// bn = lid&15.  Per XCD: 4 A-panels + 16 B-panels, 192 KB k-slice cadence.
// ---------------------------------------------------------------------------
__global__ __launch_bounds__(256, 2) void gemm_epi(
    const unsigned short* __restrict__ A,   // xs  bf16 [BB][FF]
    const unsigned short* __restrict__ Bm,  // means bf16 [CC][FF]
    const float* __restrict__ x2,           // [BB]
    const float* __restrict__ m2,           // [CC]
    float* __restrict__ expo,               // [BB][CC]
    float* __restrict__ cum) {              // [BB][CC]
    __shared__ __align__(16) unsigned short As[3][256 * 32];
    __shared__ __align__(16) unsigned short Bs[3][128 * 32];

    const int t = threadIdx.x;
    const int wave = t >> 6, lane = t & 63;
    const int bx = blockIdx.x;
    const int xcd = bx & 7, lid = bx >> 3;              // lid 0..63
    const int bm = xcd * 4 + (lid >> 4);                // 0..31
    const int bn = lid & 15;                            // 0..15
    const int rowA0 = bm * 256, colB0 = bn * 128;
    const int wm = wave >> 1, wn = wave & 1;            // 2M x 2N of 128x64

    // staging: per round, 4 waves cover 64 rows (wave*16 + sr), 64B each.
    // lane -> row-in-group lane>>2, 16B-slot lane&3; source chunk is the
    // inverse swizzle  c = slot ^ ((sr>>1)&3)  (group bases are x16).
    const int sr = lane >> 2;                           // 0..15
    const int sc = ((lane & 3) ^ ((sr >> 1) & 3)) * 8;  // source col (shorts)
    const unsigned short* gA0 = A  + (size_t)(rowA0 +   0 + wave * 16 + sr) * FF + sc;
    const unsigned short* gA1 = A  + (size_t)(rowA0 +  64 + wave * 16 + sr) * FF + sc;
    const unsigned short* gA2 = A  + (size_t)(rowA0 + 128 + wave * 16 + sr) * FF + sc;
    const unsigned short* gA3 = A  + (size_t)(rowA0 + 192 + wave * 16 + sr) * FF + sc;
    const unsigned short* gB0 = Bm + (size_t)(colB0 +   0 + wave * 16 + sr) * FF + sc;
    const unsigned short* gB1 = Bm + (size_t)(colB0 +  64 + wave * 16 + sr) * FF + sc;
    const int ldsOff = wave * 16 * 32;                  // shorts within 64-row grp

    // fragment reads (mfma 16x16x32: row = lane&15, k-half = lane>>4)
    const int rl = lane & 15, kb = lane >> 4;
    const int pcol = (kb ^ ((rl >> 1) & 3)) * 8;        // phys col (shorts)
    const int arow = (wm * 128 + rl) * 32 + pcol;
    const int brow = (wn * 64  + rl) * 32 + pcol;

    f32x4 acc[8][4] = {};

    auto STAGE = [&](int slot, int kc) {
        const int ko = kc * 32;
        async_copy16(gA0 + ko, &As[slot][0 * 64 * 32 + ldsOff]);
        async_copy16(gA1 + ko, &As[slot][1 * 64 * 32 + ldsOff]);
        async_copy16(gA2 + ko, &As[slot][2 * 64 * 32 + ldsOff]);
        async_copy16(gA3 + ko, &As[slot][3 * 64 * 32 + ldsOff]);
        async_copy16(gB0 + ko, &Bs[slot][0 * 64 * 32 + ldsOff]);
        async_copy16(gB1 + ko, &Bs[slot][1 * 64 * 32 + ldsOff]);
    };

    auto CHUNK = [&](int slot, int nslot, int kc, int vm, bool do_stage) {
        if (vm == 6) asm volatile("s_waitcnt vmcnt(6)" ::: "memory");
        else         asm volatile("s_waitcnt vmcnt(0)" ::: "memory");
        __builtin_amdgcn_s_barrier();
        __builtin_amdgcn_sched_barrier(0);
        bf16x8 af[8], bfr[4];
#pragma unroll
        for (int i = 0; i < 8; ++i) af[i] = *(const bf16x8*)&As[slot][arow + i * 16 * 32];
#pragma unroll
        for (int j = 0; j < 4; ++j) bfr[j] = *(const bf16x8*)&Bs[slot][brow + j * 16 * 32];
        if (do_stage) STAGE(nslot, kc);
        asm volatile("s_waitcnt lgkmcnt(0)" ::: "memory");
        __builtin_amdgcn_sched_barrier(0);
        __builtin_amdgcn_s_setprio(1);
#pragma unroll
        for (int i = 0; i < 8; ++i)
#pragma unroll
            for (int j = 0; j < 4; ++j)
                acc[i][j] = __builtin_amdgcn_mfma_f32_16x16x32_bf16(af[i], bfr[j], acc[i][j], 0, 0, 0);
        __builtin_amdgcn_s_setprio(0);
    };

    // prologue: 2 chunks in flight (12 loads)
    STAGE(0, 0); STAGE(1, 1);

    // chunks 0..59 (stage 2..61), then peeled 60..63 (stage 62,63, none, none)
#pragma unroll 3
    for (int u = 0; u < 60; ++u)
        CHUNK(u % 3, (u + 2) % 3, u + 2, 6, true);
    CHUNK(0, 2, 62, 6, true);    // u=60
    CHUNK(1, 0, 63, 6, true);    // u=61
    CHUNK(2, 0, 0, 6, false);    // u=62 (63's 6 loads outstanding)
    CHUNK(0, 0, 0, 0, false);    // u=63 (drain)

    // epilogue: C/D layout col = lane&15, row = (lane>>4)*4 + reg  [m89/m91]
    const int ln = lane & 15, lq = lane >> 4;
    const int grow0 = rowA0 + wm * 128 + lq * 4;
    const int gcol0 = colB0 + wn * 64 + ln;
    float m2v[4];
#pragma unroll
    for (int j = 0; j < 4; ++j) m2v[j] = m2[gcol0 + j * 16];

#pragma unroll
    for (int i = 0; i < 8; ++i) {
        float x2r[4];
#pragma unroll
        for (int r = 0; r < 4; ++r) x2r[r] = x2[grow0 + i * 16 + r];
#pragma unroll
        for (int j = 0; j < 4; ++j)
#pragma unroll
            for (int r = 0; r < 4; ++r) {
                const float d2 = x2r[r] + m2v[j] - 2.0f * acc[i][j][r];
                const float d = sqrtf(fmaxf(d2, 0.0f));
                const size_t idx = (size_t)(grow0 + i * 16 + r) * CC + (gcol0 + j * 16);
                __builtin_nontemporal_store(d, &cum[idx]);  // never re-read
                expo[idx] = -d;                              // re-read by softmax
            }
    }
}

// ---------------------------------------------------------------------------
// softmax over each row of exponent -> probs. one block (256 thr) per row.
// No max-subtraction: d = sqrt(x2+m2-2c) <= sqrt(~4500) < 68, so
// exp(-d) >= 3e-30 >> FLT_MIN — unshifted exp is safe and exact enough.
// ---------------------------------------------------------------------------
__global__ void softmax_rows(const float* __restrict__ e, float* __restrict__ p) {
    const int row = blockIdx.x;
    const int t = threadIdx.x;
    const size_t base = (size_t)row * CC + (size_t)t * 8;
    const float4 a = *(const float4*)(e + base);
    const float4 b = *(const float4*)(e + base + 4);
    float ev[8] = {__expf(a.x), __expf(a.y), __expf(a.z), __expf(a.w),
                   __expf(b.x), __expf(b.y), __expf(b.z), __expf(b.w)};
    float s = 0.0f;
#pragma unroll
    for (int i = 0; i < 8; ++i) s += ev[i];
#pragma unroll
    for (int off = 32; off > 0; off >>= 1) s += __shfl_down(s, off);
    __shared__ float reds[4];
    if ((t & 63) == 0) reds[t >> 6] = s;
    __syncthreads();
    s = (reds[0] + reds[1]) + (reds[2] + reds[3]);
    const float inv = 1.0f / s;

    f32x4 o0 = {ev[0] * inv, ev[1] * inv, ev[2] * inv, ev[3] * inv};
    f32x4 o1 = {ev[4] * inv, ev[5] * inv, ev[6] * inv, ev[7] * inv};
    __builtin_nontemporal_store(o0, (f32x4*)(p + base));
    __builtin_nontemporal_store(o1, (f32x4*)(p + base + 4));
}

// ---------------------------------------------------------------------------
extern "C" void kernel_launch(void* const* d_in, const int* in_sizes, int n_in,
                              void* d_out, int out_size, void* d_ws, size_t ws_size,
                              hipStream_t stream) {
    const float* x     = (const float*)d_in[0];   // [BB][FF]
    const float* means = (const float*)d_in[1];   // [CC][FF]
    const float* var   = (const float*)d_in[2];   // [1]
    float* out = (float*)d_out;

    // workspace layout: xb bf16 [BB*FF] | mb bf16 [CC*FF] | x2 f32[BB] | m2 f32[CC]
    unsigned short* xb = (unsigned short*)d_ws;
    unsigned short* mb = xb + (size_t)BB * FF;
    float* x2 = (float*)(mb + (size_t)CC * FF);
    float* m2 = x2 + BB;

    float* probs = out;                          // output 0
    float* expo  = out + (size_t)BB * CC;        // output 1
    float* cum   = expo + (size_t)BB * CC;       // output 2

    prep_rows<<<BB + CC, 256, 0, stream>>>(x, means, xb, mb, x2, m2, var);
    gemm_epi<<<(BB / 256) * (CC / 128), 256, 0, stream>>>(xb, mb, x2, m2, expo, cum);
    softmax_rows<<<BB, 256, 0, stream>>>(expo, probs);
}

// Round 17
// 331.372 us; speedup vs baseline: 1.0181x; 1.0018x over previous
//
#include <hip/hip_runtime.h>
#include <hip/hip_bf16.h>

// Problem constants
constexpr int BB = 8192;   // batch rows
constexpr int CC = 2048;   // classes
constexpr int FF = 2048;   // features (K)

typedef __bf16 bf16x8 __attribute__((ext_vector_type(8)));
typedef float  f32x4  __attribute__((ext_vector_type(4)));

typedef __attribute__((address_space(1))) unsigned int gu32;
typedef __attribute__((address_space(3))) unsigned int lu32;

// async global->LDS, 16B per lane. LDS side is wave-uniform base + lane*16.
__device__ __forceinline__ void async_copy16(const void* g, void* l) {
    __builtin_amdgcn_global_load_lds(
        (gu32*)(unsigned long long)g,
        (lu32*)(unsigned int)(unsigned long long)l,
        16, 0, 0);
}

// ---------------------------------------------------------------------------
// prep (merged): rows [0,BB) = x scaled by 1/var; rows [BB,BB+CC) = means.
// emit bf16 row + fp32 sum of squares. 256 thr/row, 8 elems/thread.
// ---------------------------------------------------------------------------
__global__ void prep_rows(const float* __restrict__ x,
                          const float* __restrict__ means,
                          unsigned short* __restrict__ xb,
                          unsigned short* __restrict__ mb,
                          float* __restrict__ x2,
                          float* __restrict__ m2,
                          const float* __restrict__ varp) {
    const int blk = blockIdx.x;
    const bool isx = blk < BB;
    const int row = isx ? blk : blk - BB;
    const int t = threadIdx.x;
    const float scale = isx ? (1.0f / varp[0]) : 1.0f;
    const float* in = isx ? x : means;
    unsigned short* outb = isx ? xb : mb;
    const size_t base = (size_t)row * FF + (size_t)t * 8;
    const float4 a = *(const float4*)(in + base);
    const float4 b = *(const float4*)(in + base + 4);
    float v[8] = {a.x * scale, a.y * scale, a.z * scale, a.w * scale,
                  b.x * scale, b.y * scale, b.z * scale, b.w * scale};
    float s = 0.0f;
    bf16x8 h;
#pragma unroll
    for (int i = 0; i < 8; ++i) {
        s += v[i] * v[i];
        h[i] = (__bf16)v[i];
    }
    *(bf16x8*)(outb + base) = h;
#pragma unroll
    for (int off = 32; off > 0; off >>= 1) s += __shfl_down(s, off);
    __shared__ float red[4];
    if ((t & 63) == 0) red[t >> 6] = s;
    __syncthreads();
    if (t == 0) {
        float tot = (red[0] + red[1]) + (red[2] + red[3]);
        if (isx) x2[row] = tot; else m2[row] = tot;
    }
}

// ---------------------------------------------------------------------------
// GEMM cross[b][c] = sum_f xs[b][f]*means[c][f]  (row-major, K contig: NT)
//
// R13-measured configuration (331.96 µs total — session best).  The
// barrier-free reg-direct variant (R14-16) crashed the container 3x at
// build/run and is abandoned per pre-commitment.
//
// 256x128 tile (M x N), 256 thr = 4 waves (2M x 2N), per-wave output 128x64
// via 8x4 of v_mfma_f32_16x16x32_bf16 (0.375 ds_read per MFMA).  K in
// chunks of 32 through a RING of 3 LDS slots (slot = A 256x32 + B 128x32
// bf16 = 24 KB; 72 KB total) -> 2 blocks/CU (grid 512 exact),
// __launch_bounds__(256,2).
//
// Pipeline: counted vmcnt ring (T4), 1 barrier/chunk.  Per chunk u:
// vmcnt(6) [chunk u's 6 loads landed; u+1's 6 in flight] | s_barrier |
// schedbar | 12 ds_read_b128 | STAGE(u+2 -> slot (u+2)%3: its readers
// finished ds_reads before passing THIS barrier) | lgkmcnt(0) schedbar |
// setprio{32 MFMA}.  Tail: vmcnt(6), vmcnt(6), vmcnt(0).
//
// Staging: 6 rounds x (4 waves x 16 rows x 64B linear): rounds 0-3 = A rows
// 0-255, rounds 4-5 = B rows 0-127.  LDS rows 64 B (4 x 16B chunks); phys
// chunk c' = c ^ ((row>>1)&3): frag reads 2-way banked = free (m136); XOR
// pre-applied to global source (DMA dest linear, rule #21).
//
// Block->XCD map: xcd = bx&7, lid = bx>>3 (0..63); bm = xcd*4 + lid>>4,
// bn = lid&15.  Per XCD: 4 A-panels + 16 B-panels, 192 KB k-slice cadence.
// ---------------------------------------------------------------------------
__global__ __launch_bounds__(256, 2) void gemm_epi(
    const unsigned short* __restrict__ A,   // xs  bf16 [BB][FF]
    const unsigned short* __restrict__ Bm,  // means bf16 [CC][FF]
    const float* __restrict__ x2,           // [BB]
    const float* __restrict__ m2,           // [CC]
    float* __restrict__ expo,               // [BB][CC]
    float* __restrict__ cum) {              // [BB][CC]
    __shared__ __align__(16) unsigned short As[3][256 * 32];
    __shared__ __align__(16) unsigned short Bs[3][128 * 32];

    const int t = threadIdx.x;
    const int wave = t >> 6, lane = t & 63;
    const int bx = blockIdx.x;
    const int xcd = bx & 7, lid = bx >> 3;              // lid 0..63
    const int bm = xcd * 4 + (lid >> 4);                // 0..31
    const int bn = lid & 15;                            // 0..15
    const int rowA0 = bm * 256, colB0 = bn * 128;
    const int wm = wave >> 1, wn = wave & 1;            // 2M x 2N of 128x64

    // staging: per round, 4 waves cover 64 rows (wave*16 + sr), 64B each.
    // lane -> row-in-group lane>>2, 16B-slot lane&3; source chunk is the
    // inverse swizzle  c = slot ^ ((sr>>1)&3)  (group bases are x16).
    const int sr = lane >> 2;                           // 0..15
    const int sc = ((lane & 3) ^ ((sr >> 1) & 3)) * 8;  // source col (shorts)
    const unsigned short* gA0 = A  + (size_t)(rowA0 +   0 + wave * 16 + sr) * FF + sc;
    const unsigned short* gA1 = A  + (size_t)(rowA0 +  64 + wave * 16 + sr) * FF + sc;
    const unsigned short* gA2 = A  + (size_t)(rowA0 + 128 + wave * 16 + sr) * FF + sc;
    const unsigned short* gA3 = A  + (size_t)(rowA0 + 192 + wave * 16 + sr) * FF + sc;
    const unsigned short* gB0 = Bm + (size_t)(colB0 +   0 + wave * 16 + sr) * FF + sc;
    const unsigned short* gB1 = Bm + (size_t)(colB0 +  64 + wave * 16 + sr) * FF + sc;
    const int ldsOff = wave * 16 * 32;                  // shorts within 64-row grp

    // fragment reads (mfma 16x16x32: row = lane&15, k-half = lane>>4)
    const int rl = lane & 15, kb = lane >> 4;
    const int pcol = (kb ^ ((rl >> 1) & 3)) * 8;        // phys col (shorts)
    const int arow = (wm * 128 + rl) * 32 + pcol;
    const int brow = (wn * 64  + rl) * 32 + pcol;

    f32x4 acc[8][4] = {};

    auto STAGE = [&](int slot, int kc) {
        const int ko = kc * 32;
        async_copy16(gA0 + ko, &As[slot][0 * 64 * 32 + ldsOff]);
        async_copy16(gA1 + ko, &As[slot][1 * 64 * 32 + ldsOff]);
        async_copy16(gA2 + ko, &As[slot][2 * 64 * 32 + ldsOff]);
        async_copy16(gA3 + ko, &As[slot][3 * 64 * 32 + ldsOff]);
        async_copy16(gB0 + ko, &Bs[slot][0 * 64 * 32 + ldsOff]);
        async_copy16(gB1 + ko, &Bs[slot][1 * 64 * 32 + ldsOff]);
    };

    auto CHUNK = [&](int slot, int nslot, int kc, int vm, bool do_stage) {
        if (vm == 6) asm volatile("s_waitcnt vmcnt(6)" ::: "memory");
        else         asm volatile("s_waitcnt vmcnt(0)" ::: "memory");
        __builtin_amdgcn_s_barrier();
        __builtin_amdgcn_sched_barrier(0);
        bf16x8 af[8], bfr[4];
#pragma unroll
        for (int i = 0; i < 8; ++i) af[i] = *(const bf16x8*)&As[slot][arow + i * 16 * 32];
#pragma unroll
        for (int j = 0; j < 4; ++j) bfr[j] = *(const bf16x8*)&Bs[slot][brow + j * 16 * 32];
        if (do_stage) STAGE(nslot, kc);
        asm volatile("s_waitcnt lgkmcnt(0)" ::: "memory");
        __builtin_amdgcn_sched_barrier(0);
        __builtin_amdgcn_s_setprio(1);
#pragma unroll
        for (int i = 0; i < 8; ++i)
#pragma unroll
            for (int j = 0; j < 4; ++j)
                acc[i][j] = __builtin_amdgcn_mfma_f32_16x16x32_bf16(af[i], bfr[j], acc[i][j], 0, 0, 0);
        __builtin_amdgcn_s_setprio(0);
    };

    // prologue: 2 chunks in flight (12 loads)
    STAGE(0, 0); STAGE(1, 1);

    // chunks 0..59 (stage 2..61), then peeled 60..63 (stage 62,63, none, none)
#pragma unroll 3
    for (int u = 0; u < 60; ++u)
        CHUNK(u % 3, (u + 2) % 3, u + 2, 6, true);
    CHUNK(0, 2, 62, 6, true);    // u=60
    CHUNK(1, 0, 63, 6, true);    // u=61
    CHUNK(2, 0, 0, 6, false);    // u=62 (63's 6 loads outstanding)
    CHUNK(0, 0, 0, 0, false);    // u=63 (drain)

    // epilogue: C/D layout col = lane&15, row = (lane>>4)*4 + reg  [m89/m91]
    const int ln = lane & 15, lq = lane >> 4;
    const int grow0 = rowA0 + wm * 128 + lq * 4;
    const int gcol0 = colB0 + wn * 64 + ln;
    float m2v[4];
#pragma unroll
    for (int j = 0; j < 4; ++j) m2v[j] = m2[gcol0 + j * 16];

#pragma unroll
    for (int i = 0; i < 8; ++i) {
        float x2r[4];
#pragma unroll
        for (int r = 0; r < 4; ++r) x2r[r] = x2[grow0 + i * 16 + r];
#pragma unroll
        for (int j = 0; j < 4; ++j)
#pragma unroll
            for (int r = 0; r < 4; ++r) {
                const float d2 = x2r[r] + m2v[j] - 2.0f * acc[i][j][r];
                const float d = sqrtf(fmaxf(d2, 0.0f));
                const size_t idx = (size_t)(grow0 + i * 16 + r) * CC + (gcol0 + j * 16);
                __builtin_nontemporal_store(d, &cum[idx]);  // never re-read
                expo[idx] = -d;                              // re-read by softmax
            }
    }
}

// ---------------------------------------------------------------------------
// softmax over each row of exponent -> probs. one block (256 thr) per row.
// No max-subtraction: d = sqrt(x2+m2-2c) <= sqrt(~4500) < 68, so
// exp(-d) >= 3e-30 >> FLT_MIN — unshifted exp is safe and exact enough.
// ---------------------------------------------------------------------------
__global__ void softmax_rows(const float* __restrict__ e, float* __restrict__ p) {
    const int row = blockIdx.x;
    const int t = threadIdx.x;
    const size_t base = (size_t)row * CC + (size_t)t * 8;
    const float4 a = *(const float4*)(e + base);
    const float4 b = *(const float4*)(e + base + 4);
    float ev[8] = {__expf(a.x), __expf(a.y), __expf(a.z), __expf(a.w),
                   __expf(b.x), __expf(b.y), __expf(b.z), __expf(b.w)};
    float s = 0.0f;
#pragma unroll
    for (int i = 0; i < 8; ++i) s += ev[i];
#pragma unroll
    for (int off = 32; off > 0; off >>= 1) s += __shfl_down(s, off);
    __shared__ float reds[4];
    if ((t & 63) == 0) reds[t >> 6] = s;
    __syncthreads();
    s = (reds[0] + reds[1]) + (reds[2] + reds[3]);
    const float inv = 1.0f / s;

    f32x4 o0 = {ev[0] * inv, ev[1] * inv, ev[2] * inv, ev[3] * inv};
    f32x4 o1 = {ev[4] * inv, ev[5] * inv, ev[6] * inv, ev[7] * inv};
    __builtin_nontemporal_store(o0, (f32x4*)(p + base));
    __builtin_nontemporal_store(o1, (f32x4*)(p + base + 4));
}

// ---------------------------------------------------------------------------
extern "C" void kernel_launch(void* const* d_in, const int* in_sizes, int n_in,
                              void* d_out, int out_size, void* d_ws, size_t ws_size,
                              hipStream_t stream) {
    const float* x     = (const float*)d_in[0];   // [BB][FF]
    const float* means = (const float*)d_in[1];   // [CC][FF]
    const float* var   = (const float*)d_in[2];   // [1]
    float* out = (float*)d_out;

    // workspace layout: xb bf16 [BB*FF] | mb bf16 [CC*FF] | x2 f32[BB] | m2 f32[CC]
    unsigned short* xb = (unsigned short*)d_ws;
    unsigned short* mb = xb + (size_t)BB * FF;
    float* x2 = (float*)(mb + (size_t)CC * FF);
    float* m2 = x2 + BB;

    float* probs = out;                          // output 0
    float* expo  = out + (size_t)BB * CC;        // output 1
    float* cum   = expo + (size_t)BB * CC;       // output 2

    prep_rows<<<BB + CC, 256, 0, stream>>>(x, means, xb, mb, x2, m2, var);
    gemm_epi<<<(BB / 256) * (CC / 128), 256, 0, stream>>>(xb, mb, x2, m2, expo, cum);
    softmax_rows<<<BB, 256, 0, stream>>>(expo, probs);
}